// Round 3
// baseline (807.813 us; speedup 1.0000x reference)
//
#include <hip/hip_runtime.h>
#include <cstdint>
#include <cstddef>

#define D_MODEL 2048
#define D_FFN   8192
#define RANK    16
#define EPS     1e-6f
#define MOD_SCALE 0.1f

typedef float    f32x4  __attribute__((ext_vector_type(4)));
typedef float    f32x16 __attribute__((ext_vector_type(16)));
typedef _Float16 half8  __attribute__((ext_vector_type(8)));

// Async global->LDS, 16B per lane. LDS dest is wave-uniform base + lane*16;
// the GLOBAL address is per-lane, so we XOR-swizzle the source 16B chunk
// (c ^ (row&7)) for bank-conflict-free ds_read_b128 later, at zero cost.
__device__ __forceinline__ void async_load16(const void* g, void* l) {
  __builtin_amdgcn_global_load_lds(
      (const __attribute__((address_space(1))) uint32_t*)g,
      (__attribute__((address_space(3))) uint32_t*)l,
      16, 0, 0);
}

// Stage a 128x64 f16 tile (row-major, stride in halves) into LDS, swizzled.
__device__ __forceinline__ void stage_tile(const _Float16* __restrict__ gbase,
                                           size_t stride, _Float16* lds, int tid) {
  #pragma unroll
  for (int j = 0; j < 4; ++j) {
    int idx = j * 256 + tid;          // 0..1023 chunks of 8 halves
    int row = idx >> 3;
    int c   = (idx & 7) ^ (row & 7);  // swizzled global chunk
    async_load16(gbase + (size_t)row * stride + c * 8, &lds[idx * 8]);
  }
}

// Read 8-half fragment at (row r, 8-half chunk c) from a swizzled tile.
__device__ __forceinline__ half8 frag_read(const _Float16* lds, int r, int c) {
  return *(const half8*)&lds[r * 64 + ((c ^ (r & 7)) * 8)];
}

// ---------------------------------------------------------------------------
// fp32 -> f16 elementwise convert, 8 elements/thread.
// ---------------------------------------------------------------------------
__global__ __launch_bounds__(256) void convert_f32_f16(
    const float* __restrict__ s, _Float16* __restrict__ d)
{
  size_t i = ((size_t)blockIdx.x * 256 + threadIdx.x) * 8;
  f32x4 a = *(const f32x4*)(s + i);
  f32x4 b = *(const f32x4*)(s + i + 4);
  half8 h;
  #pragma unroll
  for (int j = 0; j < 4; ++j) { h[j] = (_Float16)a[j]; h[4+j] = (_Float16)b[j]; }
  *(half8*)(d + i) = h;
}

// ---------------------------------------------------------------------------
// Kernel 1: per-token RMSNorm -> h (f16), and
//           c[m,r] = (h.A)[r] * 0.1*tanh((attn.A)[r])
// ---------------------------------------------------------------------------
__global__ __launch_bounds__(256) void prep_kernel(
    const float* __restrict__ hs, const float* __restrict__ attn,
    const float* __restrict__ Amat, const float* __restrict__ gamma,
    _Float16* __restrict__ h16, float* __restrict__ cmat)
{
  const int token = blockIdx.x;
  const int tid   = threadIdx.x;
  const int lane  = tid & 63;
  const int wv    = tid >> 6;
  const size_t tb = (size_t)token * D_MODEL;
  const int base  = tid * 8;

  f32x4 x0 = *(const f32x4*)(hs + tb + base);
  f32x4 x1 = *(const f32x4*)(hs + tb + base + 4);
  f32x4 a0 = *(const f32x4*)(attn + tb + base);
  f32x4 a1 = *(const f32x4*)(attn + tb + base + 4);

  float ss = 0.f;
  #pragma unroll
  for (int j = 0; j < 4; ++j) ss += x0[j]*x0[j] + x1[j]*x1[j];
  #pragma unroll
  for (int off = 32; off > 0; off >>= 1) ss += __shfl_xor(ss, off, 64);

  __shared__ float red[4];
  __shared__ float redp[4][RANK];
  __shared__ float redh[4][RANK];
  if (lane == 0) red[wv] = ss;
  __syncthreads();
  const float tot = red[0] + red[1] + red[2] + red[3];
  const float rms = rsqrtf(tot * (1.0f / D_MODEL) + EPS);

  f32x4 g0 = *(const f32x4*)(gamma + base);
  f32x4 g1 = *(const f32x4*)(gamma + base + 4);
  float hv[8], av[8];
  #pragma unroll
  for (int j = 0; j < 4; ++j) {
    hv[j]   = x0[j] * rms * g0[j];
    hv[4+j] = x1[j] * rms * g1[j];
    av[j]   = a0[j];
    av[4+j] = a1[j];
  }
  half8 hh;
  #pragma unroll
  for (int j = 0; j < 8; ++j) hh[j] = (_Float16)hv[j];
  *(half8*)(h16 + tb + base) = hh;

  float pa[RANK], ph[RANK];
  #pragma unroll
  for (int r = 0; r < RANK; ++r) { pa[r] = 0.f; ph[r] = 0.f; }
  #pragma unroll
  for (int e = 0; e < 8; ++e) {
    const f32x4* Ar = (const f32x4*)(Amat + (size_t)(base + e) * RANK);
    #pragma unroll
    for (int q = 0; q < 4; ++q) {
      f32x4 ar = Ar[q];
      #pragma unroll
      for (int j = 0; j < 4; ++j) {
        pa[q*4+j] += av[e] * ar[j];
        ph[q*4+j] += hv[e] * ar[j];
      }
    }
  }
  #pragma unroll
  for (int r = 0; r < RANK; ++r) {
    #pragma unroll
    for (int off = 32; off > 0; off >>= 1) {
      pa[r] += __shfl_xor(pa[r], off, 64);
      ph[r] += __shfl_xor(ph[r], off, 64);
    }
  }
  if (lane == 0) {
    #pragma unroll
    for (int r = 0; r < RANK; ++r) { redp[wv][r] = pa[r]; redh[wv][r] = ph[r]; }
  }
  __syncthreads();
  if (tid < RANK) {
    float sp = redp[0][tid] + redp[1][tid] + redp[2][tid] + redp[3][tid];
    float sh = redh[0][tid] + redh[1][tid] + redh[2][tid] + redh[3][tid];
    cmat[(size_t)token * RANK + tid] = sh * (MOD_SCALE * tanhf(sp));
  }
}

// ---------------------------------------------------------------------------
// Kernel 2: dual GEMM  gate = h@Wg16^T (+ rank-16 delta), up = h@Wu16^T;
//           t = silu(gate)*up (f16). 128x128 tile, BK=64, 32x32x16 MFMA,
//           wave tile 64x64 = 2x2 tiles of 32x32, all-async staging.
// ---------------------------------------------------------------------------
__global__ __launch_bounds__(256, 2) void gemm_gateup(
    const _Float16* __restrict__ h16,
    const _Float16* __restrict__ Wg16, const _Float16* __restrict__ Wu16,
    const float* __restrict__ cmat, const float* __restrict__ Bmat,
    _Float16* __restrict__ tmat)
{
  __shared__ __align__(16) _Float16 sA [128*64];
  __shared__ __align__(16) _Float16 sB1[128*64];
  __shared__ __align__(16) _Float16 sB2[128*64];

  const int tid  = threadIdx.x;
  const int lane = tid & 63;
  const int wv   = tid >> 6;
  const int wm   = (wv >> 1) * 64;
  const int wn   = (wv & 1) * 64;
  const int l31  = lane & 31;
  const int h32  = lane >> 5;       // 0/1: which k-half of the fragment
  const int gm0  = blockIdx.y * 128;
  const int gn0  = blockIdx.x * 128;

  f32x16 accG[2][2], accU[2][2];
  #pragma unroll
  for (int i = 0; i < 2; ++i)
    #pragma unroll
    for (int j = 0; j < 2; ++j) {
      accG[i][j] = (f32x16)(0.0f);
      accU[i][j] = (f32x16)(0.0f);
    }

  for (int kt = 0; kt < D_MODEL / 64; ++kt) {
    __syncthreads();
    stage_tile(h16  + (size_t)gm0 * D_MODEL + kt * 64, D_MODEL, sA,  tid);
    stage_tile(Wg16 + (size_t)gn0 * D_MODEL + kt * 64, D_MODEL, sB1, tid);
    stage_tile(Wu16 + (size_t)gn0 * D_MODEL + kt * 64, D_MODEL, sB2, tid);
    __syncthreads();
    #pragma unroll
    for (int kc = 0; kc < 4; ++kc) {        // 4 x K=16
      const int ck = kc * 2 + h32;          // 8-half chunk along the 64-half row
      half8 af[2], bg[2], bu[2];
      #pragma unroll
      for (int im = 0; im < 2; ++im)
        af[im] = frag_read(sA, wm + im * 32 + l31, ck);
      #pragma unroll
      for (int in = 0; in < 2; ++in) {
        bg[in] = frag_read(sB1, wn + in * 32 + l31, ck);
        bu[in] = frag_read(sB2, wn + in * 32 + l31, ck);
      }
      #pragma unroll
      for (int im = 0; im < 2; ++im)
        #pragma unroll
        for (int in = 0; in < 2; ++in) {
          accG[im][in] = __builtin_amdgcn_mfma_f32_32x32x16_f16(af[im], bg[in], accG[im][in], 0, 0, 0);
          accU[im][in] = __builtin_amdgcn_mfma_f32_32x32x16_f16(af[im], bu[in], accU[im][in], 0, 0, 0);
        }
    }
  }

  // rank-16 delta: one exact K=16 32x32x16 MFMA per tile pair into accG.
  // sC[128][16] <- cmat (A-layout), sD[128][16] <- Bmat^T (B-layout).
  _Float16* sC = sA;
  _Float16* sD = sA + 128 * 16;
  __syncthreads();
  {
    int m = tid >> 1, k0 = (tid & 1) * 8;
    f32x4 c0 = *(const f32x4*)(cmat + (size_t)(gm0 + m) * RANK + k0);
    f32x4 c1 = *(const f32x4*)(cmat + (size_t)(gm0 + m) * RANK + k0 + 4);
    half8 hc;
    #pragma unroll
    for (int j = 0; j < 4; ++j) { hc[j] = (_Float16)c0[j]; hc[4+j] = (_Float16)c1[j]; }
    *(half8*)&sC[m * 16 + k0] = hc;

    int kk = tid >> 4, n0 = (tid & 15) * 8;
    f32x4 b0 = *(const f32x4*)(Bmat + (size_t)kk * D_FFN + gn0 + n0);
    f32x4 b1 = *(const f32x4*)(Bmat + (size_t)kk * D_FFN + gn0 + n0 + 4);
    #pragma unroll
    for (int j = 0; j < 4; ++j) {
      sD[(n0 + j) * 16 + kk]     = (_Float16)b0[j];
      sD[(n0 + 4 + j) * 16 + kk] = (_Float16)b1[j];
    }
  }
  __syncthreads();
  {
    half8 af[2], bd[2];
    #pragma unroll
    for (int im = 0; im < 2; ++im)
      af[im] = *(const half8*)&sC[(wm + im * 32 + l31) * 16 + h32 * 8];
    #pragma unroll
    for (int in = 0; in < 2; ++in)
      bd[in] = *(const half8*)&sD[(wn + in * 32 + l31) * 16 + h32 * 8];
    #pragma unroll
    for (int im = 0; im < 2; ++im)
      #pragma unroll
      for (int in = 0; in < 2; ++in)
        accG[im][in] = __builtin_amdgcn_mfma_f32_32x32x16_f16(af[im], bd[in], accG[im][in], 0, 0, 0);
  }

  // Epilogue: t = silu(gate) * up.  C/D: row=(r&3)+8*(r>>2)+4*h32, col=l31.
  #pragma unroll
  for (int im = 0; im < 2; ++im)
    #pragma unroll
    for (int in = 0; in < 2; ++in) {
      const int col = gn0 + wn + in * 32 + l31;
      #pragma unroll
      for (int r = 0; r < 16; ++r) {
        const int row = gm0 + wm + im * 32 + (r & 3) + 8 * (r >> 2) + 4 * h32;
        float g = accG[im][in][r];
        float u = accU[im][in][r];
        float s = g / (1.0f + __expf(-g));
        tmat[(size_t)row * D_FFN + col] = (_Float16)(s * u);
      }
    }
}

// ---------------------------------------------------------------------------
// Kernel 3: out = hidden_states + t @ Wd16^T   (K = 8192), fp32 out.
// acc only 64 AGPRs -> ask for 3 waves/EU (3 blocks/CU) for latency hiding.
// ---------------------------------------------------------------------------
__global__ __launch_bounds__(256, 3) void gemm_down(
    const _Float16* __restrict__ tmat, const _Float16* __restrict__ Wd16,
    const float* __restrict__ hs, float* __restrict__ out)
{
  __shared__ __align__(16) _Float16 sA[128*64];
  __shared__ __align__(16) _Float16 sB[128*64];

  const int tid  = threadIdx.x;
  const int lane = tid & 63;
  const int wv   = tid >> 6;
  const int wm   = (wv >> 1) * 64;
  const int wn   = (wv & 1) * 64;
  const int l31  = lane & 31;
  const int h32  = lane >> 5;
  const int gm0  = blockIdx.y * 128;
  const int gn0  = blockIdx.x * 128;

  f32x16 acc[2][2];
  #pragma unroll
  for (int i = 0; i < 2; ++i)
    #pragma unroll
    for (int j = 0; j < 2; ++j)
      acc[i][j] = (f32x16)(0.0f);

  for (int kt = 0; kt < D_FFN / 64; ++kt) {
    __syncthreads();
    stage_tile(tmat + (size_t)gm0 * D_FFN + kt * 64, D_FFN, sA, tid);
    stage_tile(Wd16 + (size_t)gn0 * D_FFN + kt * 64, D_FFN, sB, tid);
    __syncthreads();
    #pragma unroll
    for (int kc = 0; kc < 4; ++kc) {
      const int ck = kc * 2 + h32;
      half8 af[2], bf_[2];
      #pragma unroll
      for (int im = 0; im < 2; ++im)
        af[im] = frag_read(sA, wm + im * 32 + l31, ck);
      #pragma unroll
      for (int in = 0; in < 2; ++in)
        bf_[in] = frag_read(sB, wn + in * 32 + l31, ck);
      #pragma unroll
      for (int im = 0; im < 2; ++im)
        #pragma unroll
        for (int in = 0; in < 2; ++in)
          acc[im][in] = __builtin_amdgcn_mfma_f32_32x32x16_f16(af[im], bf_[in], acc[im][in], 0, 0, 0);
    }
  }

  #pragma unroll
  for (int im = 0; im < 2; ++im)
    #pragma unroll
    for (int in = 0; in < 2; ++in) {
      const int col = gn0 + wn + in * 32 + l31;
      #pragma unroll
      for (int r = 0; r < 16; ++r) {
        const int row = gm0 + wm + im * 32 + (r & 3) + 8 * (r >> 2) + 4 * h32;
        size_t o = (size_t)row * D_MODEL + col;
        out[o] = hs[o] + acc[im][in][r];
      }
    }
}

extern "C" void kernel_launch(void* const* d_in, const int* in_sizes, int n_in,
                              void* d_out, int out_size, void* d_ws, size_t ws_size,
                              hipStream_t stream) {
  const float* hs    = (const float*)d_in[0];
  const float* attn  = (const float*)d_in[1];
  const float* Amat  = (const float*)d_in[2];
  const float* Bmat  = (const float*)d_in[3];
  const float* Wg    = (const float*)d_in[4];
  const float* Wu    = (const float*)d_in[5];
  const float* Wd    = (const float*)d_in[6];
  const float* gamma = (const float*)d_in[7];
  float* out = (float*)d_out;

  const int M = in_sizes[0] / D_MODEL;        // 4096 tokens
  const size_t WD = (size_t)D_FFN * D_MODEL;  // elements per big weight

  // ws layout:
  //   h16   M*D f16, cmat M*16 f32, tmat M*F f16, wbuf 2*WD f16 (Wg16|Wu16)
  //   [opt] wd_sep WD f16 — only if ws_size permits; else Wd16 aliases Wg16
  //   (stream-ordered reuse after gateup has consumed it).
  char* ws = (char*)d_ws;
  _Float16* h16  = (_Float16*)ws;
  float*    cmat = (float*)(ws + (size_t)M * D_MODEL * 2);
  _Float16* tmat = (_Float16*)(ws + (size_t)M * D_MODEL * 2 + (size_t)M * RANK * 4);
  _Float16* wbuf = tmat + (size_t)M * D_FFN;
  _Float16* Wg16 = wbuf;
  _Float16* Wu16 = wbuf + WD;

  const size_t base_bytes = (size_t)M * D_MODEL * 2 + (size_t)M * RANK * 4
                          + (size_t)M * D_FFN * 2 + 2 * WD * 2;
  const bool sep_wd = (ws_size >= base_bytes + WD * 2);
  _Float16* Wd16 = sep_wd ? (wbuf + 2 * WD) : wbuf;

  const int convBlocks = (int)(WD / (256 * 8));   // 8192

  prep_kernel<<<M, 256, 0, stream>>>(hs, attn, Amat, gamma, h16, cmat);
  convert_f32_f16<<<convBlocks, 256, 0, stream>>>(Wg, Wg16);
  convert_f32_f16<<<convBlocks, 256, 0, stream>>>(Wu, Wu16);
  if (sep_wd) convert_f32_f16<<<convBlocks, 256, 0, stream>>>(Wd, Wd16);
  gemm_gateup<<<dim3(D_FFN / 128, M / 128), 256, 0, stream>>>(h16, Wg16, Wu16, cmat, Bmat, tmat);
  if (!sep_wd) convert_f32_f16<<<convBlocks, 256, 0, stream>>>(Wd, Wd16);
  gemm_down<<<dim3(D_MODEL / 128, M / 128), 256, 0, stream>>>(tmat, Wd16, hs, out);
}

// Round 4
// 769.335 us; speedup vs baseline: 1.0500x; 1.0500x over previous
//
#include <hip/hip_runtime.h>
#include <cstdint>
#include <cstddef>

#define D_MODEL 2048
#define D_FFN   8192
#define RANK    16
#define EPS     1e-6f
#define MOD_SCALE 0.1f

typedef float    f32x4 __attribute__((ext_vector_type(4)));
typedef _Float16 half8 __attribute__((ext_vector_type(8)));

// Async global->LDS, 16B per lane. LDS dest is wave-uniform base + lane*16;
// the GLOBAL address is per-lane, so we XOR-swizzle the source 16B chunk
// (c ^ (row&7)) for bank-conflict-free ds_read_b128 later, at zero cost.
// NOTE (R3 post-mortem): this swizzle is conflict-free ONLY with the 16x16
// quad-based fragment addressing below (measured 2.6e5 vs 2.7e7 conflicts
// for the 32-row / h32-chunk pattern). Do not switch to 32x32 MFMA without
// re-deriving the swizzle.
__device__ __forceinline__ void async_load16(const void* g, void* l) {
  __builtin_amdgcn_global_load_lds(
      (const __attribute__((address_space(1))) uint32_t*)g,
      (__attribute__((address_space(3))) uint32_t*)l,
      16, 0, 0);
}

// Stage a 128x64 f16 tile (row-major, stride in halves) into LDS, swizzled.
__device__ __forceinline__ void stage_tile(const _Float16* __restrict__ gbase,
                                           size_t stride, _Float16* lds, int tid) {
  #pragma unroll
  for (int j = 0; j < 4; ++j) {
    int idx = j * 256 + tid;          // 0..1023 chunks of 8 halves
    int row = idx >> 3;
    int c   = (idx & 7) ^ (row & 7);  // swizzled global chunk
    async_load16(gbase + (size_t)row * stride + c * 8, &lds[idx * 8]);
  }
}

// Read 8-half fragment at (row r, 8-half chunk c) from a swizzled tile.
__device__ __forceinline__ half8 frag_read(const _Float16* lds, int r, int c) {
  return *(const half8*)&lds[r * 64 + ((c ^ (r & 7)) * 8)];
}

// ---------------------------------------------------------------------------
// Fused fp32 -> f16 convert for all three big weights (one launch).
// 8192 blocks per weight; blockIdx.x >> 13 selects the weight.
// ---------------------------------------------------------------------------
__global__ __launch_bounds__(256) void convert3_f32_f16(
    const float* __restrict__ s0, const float* __restrict__ s1,
    const float* __restrict__ s2,
    _Float16* __restrict__ d0, _Float16* __restrict__ d1,
    _Float16* __restrict__ d2)
{
  const int w = blockIdx.x >> 13;
  const float*   s = (w == 0) ? s0 : (w == 1) ? s1 : s2;
  _Float16*      d = (w == 0) ? d0 : (w == 1) ? d1 : d2;
  size_t i = ((size_t)(blockIdx.x & 8191) * 256 + threadIdx.x) * 8;
  f32x4 a = *(const f32x4*)(s + i);
  f32x4 b = *(const f32x4*)(s + i + 4);
  half8 h;
  #pragma unroll
  for (int j = 0; j < 4; ++j) { h[j] = (_Float16)a[j]; h[4+j] = (_Float16)b[j]; }
  *(half8*)(d + i) = h;
}

__global__ __launch_bounds__(256) void convert_f32_f16(
    const float* __restrict__ s, _Float16* __restrict__ d)
{
  size_t i = ((size_t)blockIdx.x * 256 + threadIdx.x) * 8;
  f32x4 a = *(const f32x4*)(s + i);
  f32x4 b = *(const f32x4*)(s + i + 4);
  half8 h;
  #pragma unroll
  for (int j = 0; j < 4; ++j) { h[j] = (_Float16)a[j]; h[4+j] = (_Float16)b[j]; }
  *(half8*)(d + i) = h;
}

// ---------------------------------------------------------------------------
// Kernel 1: per-token RMSNorm -> h (f16), and
//           c[m,r] = (h.A)[r] * 0.1*tanh((attn.A)[r])
// ---------------------------------------------------------------------------
__global__ __launch_bounds__(256) void prep_kernel(
    const float* __restrict__ hs, const float* __restrict__ attn,
    const float* __restrict__ Amat, const float* __restrict__ gamma,
    _Float16* __restrict__ h16, float* __restrict__ cmat)
{
  const int token = blockIdx.x;
  const int tid   = threadIdx.x;
  const int lane  = tid & 63;
  const int wv    = tid >> 6;
  const size_t tb = (size_t)token * D_MODEL;
  const int base  = tid * 8;

  f32x4 x0 = *(const f32x4*)(hs + tb + base);
  f32x4 x1 = *(const f32x4*)(hs + tb + base + 4);
  f32x4 a0 = *(const f32x4*)(attn + tb + base);
  f32x4 a1 = *(const f32x4*)(attn + tb + base + 4);

  float ss = 0.f;
  #pragma unroll
  for (int j = 0; j < 4; ++j) ss += x0[j]*x0[j] + x1[j]*x1[j];
  #pragma unroll
  for (int off = 32; off > 0; off >>= 1) ss += __shfl_xor(ss, off, 64);

  __shared__ float red[4];
  __shared__ float redp[4][RANK];
  __shared__ float redh[4][RANK];
  if (lane == 0) red[wv] = ss;
  __syncthreads();
  const float tot = red[0] + red[1] + red[2] + red[3];
  const float rms = rsqrtf(tot * (1.0f / D_MODEL) + EPS);

  f32x4 g0 = *(const f32x4*)(gamma + base);
  f32x4 g1 = *(const f32x4*)(gamma + base + 4);
  float hv[8], av[8];
  #pragma unroll
  for (int j = 0; j < 4; ++j) {
    hv[j]   = x0[j] * rms * g0[j];
    hv[4+j] = x1[j] * rms * g1[j];
    av[j]   = a0[j];
    av[4+j] = a1[j];
  }
  half8 hh;
  #pragma unroll
  for (int j = 0; j < 8; ++j) hh[j] = (_Float16)hv[j];
  *(half8*)(h16 + tb + base) = hh;

  float pa[RANK], ph[RANK];
  #pragma unroll
  for (int r = 0; r < RANK; ++r) { pa[r] = 0.f; ph[r] = 0.f; }
  #pragma unroll
  for (int e = 0; e < 8; ++e) {
    const f32x4* Ar = (const f32x4*)(Amat + (size_t)(base + e) * RANK);
    #pragma unroll
    for (int q = 0; q < 4; ++q) {
      f32x4 ar = Ar[q];
      #pragma unroll
      for (int j = 0; j < 4; ++j) {
        pa[q*4+j] += av[e] * ar[j];
        ph[q*4+j] += hv[e] * ar[j];
      }
    }
  }
  #pragma unroll
  for (int r = 0; r < RANK; ++r) {
    #pragma unroll
    for (int off = 32; off > 0; off >>= 1) {
      pa[r] += __shfl_xor(pa[r], off, 64);
      ph[r] += __shfl_xor(ph[r], off, 64);
    }
  }
  if (lane == 0) {
    #pragma unroll
    for (int r = 0; r < RANK; ++r) { redp[wv][r] = pa[r]; redh[wv][r] = ph[r]; }
  }
  __syncthreads();
  if (tid < RANK) {
    float sp = redp[0][tid] + redp[1][tid] + redp[2][tid] + redp[3][tid];
    float sh = redh[0][tid] + redh[1][tid] + redh[2][tid] + redh[3][tid];
    cmat[(size_t)token * RANK + tid] = sh * (MOD_SCALE * tanhf(sp));
  }
}

// ---------------------------------------------------------------------------
// Kernel 2: dual GEMM  gate = h@Wg16^T (+ rank-16 delta), up = h@Wu16^T;
//           t = silu(gate)*up (f16). 128x128 tile, BK=64, 16x16x32 MFMA
//           (R2-proven: 47% MfmaUtil, conflict-free with the XOR swizzle).
// ---------------------------------------------------------------------------
__global__ __launch_bounds__(256, 2) void gemm_gateup(
    const _Float16* __restrict__ h16,
    const _Float16* __restrict__ Wg16, const _Float16* __restrict__ Wu16,
    const float* __restrict__ cmat, const float* __restrict__ Bmat,
    _Float16* __restrict__ tmat)
{
  __shared__ __align__(16) _Float16 sA [128*64];
  __shared__ __align__(16) _Float16 sB1[128*64];
  __shared__ __align__(16) _Float16 sB2[128*64];

  const int tid  = threadIdx.x;
  const int lane = tid & 63;
  const int wv   = tid >> 6;
  const int wm   = (wv >> 1) * 64;
  const int wn   = (wv & 1) * 64;
  const int lr   = lane & 15;
  const int quad = lane >> 4;
  const int gm0  = blockIdx.y * 128;
  const int gn0  = blockIdx.x * 128;

  f32x4 accG[4][4], accU[4][4];
  #pragma unroll
  for (int i = 0; i < 4; ++i)
    #pragma unroll
    for (int j = 0; j < 4; ++j) {
      f32x4 z = {0.f, 0.f, 0.f, 0.f};
      accG[i][j] = z; accU[i][j] = z;
    }

  for (int kt = 0; kt < D_MODEL / 64; ++kt) {
    __syncthreads();
    stage_tile(h16  + (size_t)gm0 * D_MODEL + kt * 64, D_MODEL, sA,  tid);
    stage_tile(Wg16 + (size_t)gn0 * D_MODEL + kt * 64, D_MODEL, sB1, tid);
    stage_tile(Wu16 + (size_t)gn0 * D_MODEL + kt * 64, D_MODEL, sB2, tid);
    __syncthreads();
    #pragma unroll
    for (int ks = 0; ks < 2; ++ks) {
      const int ck = ks * 4 + quad;         // 8-half chunk index along K
      half8 af[4], bg[4], bu[4];
      #pragma unroll
      for (int im = 0; im < 4; ++im)
        af[im] = frag_read(sA, wm + im * 16 + lr, ck);
      #pragma unroll
      for (int in = 0; in < 4; ++in) {
        bg[in] = frag_read(sB1, wn + in * 16 + lr, ck);
        bu[in] = frag_read(sB2, wn + in * 16 + lr, ck);
      }
      #pragma unroll
      for (int im = 0; im < 4; ++im)
        #pragma unroll
        for (int in = 0; in < 4; ++in) {
          accG[im][in] = __builtin_amdgcn_mfma_f32_16x16x32_f16(af[im], bg[in], accG[im][in], 0, 0, 0);
          accU[im][in] = __builtin_amdgcn_mfma_f32_16x16x32_f16(af[im], bu[in], accU[im][in], 0, 0, 0);
        }
    }
  }

  // rank-16 delta folded in as one zero-padded K=32 MFMA step into accG.
  __syncthreads();
  #pragma unroll
  for (int i = 0; i < 16; ++i) {
    int idx = i * 256 + tid;              // 0..4095
    int m = idx >> 5, kk = idx & 31;
    sA[idx]  = (kk < RANK) ? (_Float16)cmat[(size_t)(gm0 + m) * RANK + kk] : (_Float16)0.0f;
    sB1[idx] = (kk < RANK) ? (_Float16)Bmat[(size_t)kk * D_FFN + gn0 + m]  : (_Float16)0.0f;
  }
  __syncthreads();
  {
    const int ko = quad * 8;
    half8 af[4], bd[4];
    #pragma unroll
    for (int im = 0; im < 4; ++im)
      af[im] = *(const half8*)&sA[(wm + im * 16 + lr) * 32 + ko];
    #pragma unroll
    for (int in = 0; in < 4; ++in)
      bd[in] = *(const half8*)&sB1[(wn + in * 16 + lr) * 32 + ko];
    #pragma unroll
    for (int im = 0; im < 4; ++im)
      #pragma unroll
      for (int in = 0; in < 4; ++in)
        accG[im][in] = __builtin_amdgcn_mfma_f32_16x16x32_f16(af[im], bd[in], accG[im][in], 0, 0, 0);
  }

  // Epilogue: t = silu(gate) * up
  #pragma unroll
  for (int im = 0; im < 4; ++im)
    #pragma unroll
    for (int in = 0; in < 4; ++in) {
      const int growb = gm0 + wm + im * 16 + quad * 4;
      const int gcol  = gn0 + wn + in * 16 + lr;
      #pragma unroll
      for (int r = 0; r < 4; ++r) {
        float g = accG[im][in][r];
        float u = accU[im][in][r];
        float s = g / (1.0f + __expf(-g));
        tmat[(size_t)(growb + r) * D_FFN + gcol] = (_Float16)(s * u);
      }
    }
}

// ---------------------------------------------------------------------------
// Kernel 3: out = hidden_states + t @ Wd16^T   (K = 8192), fp32 out.
// Single 64-AGPR accumulator -> 3 waves/EU for extra latency hiding.
// ---------------------------------------------------------------------------
__global__ __launch_bounds__(256, 3) void gemm_down(
    const _Float16* __restrict__ tmat, const _Float16* __restrict__ Wd16,
    const float* __restrict__ hs, float* __restrict__ out)
{
  __shared__ __align__(16) _Float16 sA[128*64];
  __shared__ __align__(16) _Float16 sB[128*64];

  const int tid  = threadIdx.x;
  const int lane = tid & 63;
  const int wv   = tid >> 6;
  const int wm   = (wv >> 1) * 64;
  const int wn   = (wv & 1) * 64;
  const int lr   = lane & 15;
  const int quad = lane >> 4;
  const int gm0  = blockIdx.y * 128;
  const int gn0  = blockIdx.x * 128;

  f32x4 acc[4][4];
  #pragma unroll
  for (int i = 0; i < 4; ++i)
    #pragma unroll
    for (int j = 0; j < 4; ++j) {
      f32x4 z = {0.f, 0.f, 0.f, 0.f};
      acc[i][j] = z;
    }

  for (int kt = 0; kt < D_FFN / 64; ++kt) {
    __syncthreads();
    stage_tile(tmat + (size_t)gm0 * D_FFN + kt * 64, D_FFN, sA, tid);
    stage_tile(Wd16 + (size_t)gn0 * D_FFN + kt * 64, D_FFN, sB, tid);
    __syncthreads();
    #pragma unroll
    for (int ks = 0; ks < 2; ++ks) {
      const int ck = ks * 4 + quad;
      half8 af[4], bf_[4];
      #pragma unroll
      for (int im = 0; im < 4; ++im)
        af[im] = frag_read(sA, wm + im * 16 + lr, ck);
      #pragma unroll
      for (int in = 0; in < 4; ++in)
        bf_[in] = frag_read(sB, wn + in * 16 + lr, ck);
      #pragma unroll
      for (int im = 0; im < 4; ++im)
        #pragma unroll
        for (int in = 0; in < 4; ++in)
          acc[im][in] = __builtin_amdgcn_mfma_f32_16x16x32_f16(af[im], bf_[in], acc[im][in], 0, 0, 0);
    }
  }

  #pragma unroll
  for (int im = 0; im < 4; ++im)
    #pragma unroll
    for (int in = 0; in < 4; ++in) {
      const int growb = gm0 + wm + im * 16 + quad * 4;
      const int gcol  = gn0 + wn + in * 16 + lr;
      #pragma unroll
      for (int r = 0; r < 4; ++r) {
        size_t o = (size_t)(growb + r) * D_MODEL + gcol;
        out[o] = hs[o] + acc[im][in][r];
      }
    }
}

extern "C" void kernel_launch(void* const* d_in, const int* in_sizes, int n_in,
                              void* d_out, int out_size, void* d_ws, size_t ws_size,
                              hipStream_t stream) {
  const float* hs    = (const float*)d_in[0];
  const float* attn  = (const float*)d_in[1];
  const float* Amat  = (const float*)d_in[2];
  const float* Bmat  = (const float*)d_in[3];
  const float* Wg    = (const float*)d_in[4];
  const float* Wu    = (const float*)d_in[5];
  const float* Wd    = (const float*)d_in[6];
  const float* gamma = (const float*)d_in[7];
  float* out = (float*)d_out;

  const int M = in_sizes[0] / D_MODEL;        // 4096 tokens
  const size_t WD = (size_t)D_FFN * D_MODEL;  // elements per big weight

  // ws layout:
  //   h16 M*D f16 | cmat M*16 f32 | tmat M*F f16 | Wg16 | Wu16 | [Wd16 if fits]
  char* ws = (char*)d_ws;
  _Float16* h16  = (_Float16*)ws;
  float*    cmat = (float*)(ws + (size_t)M * D_MODEL * 2);
  _Float16* tmat = (_Float16*)(ws + (size_t)M * D_MODEL * 2 + (size_t)M * RANK * 4);
  _Float16* wbuf = tmat + (size_t)M * D_FFN;
  _Float16* Wg16 = wbuf;
  _Float16* Wu16 = wbuf + WD;

  const size_t base_bytes = (size_t)M * D_MODEL * 2 + (size_t)M * RANK * 4
                          + (size_t)M * D_FFN * 2 + 2 * WD * 2;
  const bool sep_wd = (ws_size >= base_bytes + WD * 2);
  _Float16* Wd16 = sep_wd ? (wbuf + 2 * WD) : wbuf;   // else reuse Wg16 slot

  const int convBlocks = (int)(WD / (256 * 8));   // 8192 per weight

  prep_kernel<<<M, 256, 0, stream>>>(hs, attn, Amat, gamma, h16, cmat);
  if (sep_wd) {
    convert3_f32_f16<<<3 * convBlocks, 256, 0, stream>>>(Wg, Wu, Wd, Wg16, Wu16, Wd16);
    gemm_gateup<<<dim3(D_FFN / 128, M / 128), 256, 0, stream>>>(h16, Wg16, Wu16, cmat, Bmat, tmat);
  } else {
    convert_f32_f16<<<convBlocks, 256, 0, stream>>>(Wg, Wg16);
    convert_f32_f16<<<convBlocks, 256, 0, stream>>>(Wu, Wu16);
    gemm_gateup<<<dim3(D_FFN / 128, M / 128), 256, 0, stream>>>(h16, Wg16, Wu16, cmat, Bmat, tmat);
    convert_f32_f16<<<convBlocks, 256, 0, stream>>>(Wd, Wd16);
  }
  gemm_down<<<dim3(D_MODEL / 128, M / 128), 256, 0, stream>>>(tmat, Wd16, hs, out);
}